// Round 8
// baseline (90.174 us; speedup 1.0000x reference)
//
#include <hip/hip_runtime.h>
#include <hip/hip_bf16.h>

// MeanPooling: out[b,e,d] = (sum_l map[b,e,l]*doc[b,l,d]) / lens[b,e]
// B=16, E=256, L=4096 (=K), D=512. fp32 in/out, bf16 MFMA inside.
//
// R8: logical-fabric-traffic fix. R2-R7 all plateau at ~81-85us = 512MB-1GB
// logical panel traffic at the ~6.3 TB/s LLC/fabric ceiling (L2 captures no
// cross-block reuse; per-CU rate measured at exactly the 11.7 B/cy fabric
// share). Traffic = (D/BN)|emap| + (E/BM)|doc|. BM=256 (full E) + BN=256:
// 268MB + ~40MB atomic RMW vs R7's 536MB.
//  - Grid 128 = 16b x 2dt x 4ks (split-K x4, KPW=1024). 8 waves/block.
//  - Wave tile 128x64 (wr=w>>2, wc=w&3): acc 8x4 f32x4 = 128 VGPR.
//  - Staging: A 4x dwordx4/thread, B 16x dword/thread (R7 k-column pattern),
//    bf16 into LDS; B transposed at ds_write ([d][k], chunk^=(d>>2)&3, R7
//    bit-exact); A' granule swizzle ^=(row>>1)&3 (8-way -> 2-way reads).
//  - Phase order puts only ONE staging reg-set live through MFMA (~240 VGPR).
//  - Depth-2 LDS pingpong, counted vmcnt(20), raw s_barrier, clamped tail.
//  - XCD swizzle: XCD owns 2 whole batches (all dt/ks siblings) -> atomic
//    lines L2-local. memsetAsync + unsafeAtomicAdd epilogue (R7-verified).

#define NB 16
#define NE 256
#define NL 4096
#define ND 512
#define KSPLIT 4
#define KPW (NL / KSPLIT)   // 1024 per block
#define BK 32
#define NT (KPW / BK)       // 32 k-steps

using f32x4  = __attribute__((ext_vector_type(4))) float;
using u32x4  = __attribute__((ext_vector_type(4))) unsigned;
using bf16x8 = __attribute__((ext_vector_type(8))) short;

static __device__ __forceinline__ unsigned bfbits(float x) {
  return (unsigned)__builtin_bit_cast(unsigned short, (__bf16)x);  // RNE
}
static __device__ __forceinline__ unsigned lds_u32(const void* p) {
  return (unsigned)(size_t)(const __attribute__((address_space(3))) void*)p;
}

#define GLOADX4(DST, PTR) \
  asm volatile("global_load_dwordx4 %0, %1, off" : "=v"(DST) : "v"(PTR))
#define GLOADX1(DST, PTR) \
  asm volatile("global_load_dword %0, %1, off" : "=v"(DST) : "v"(PTR))
#define DSWRITE64(ADDR, LO, HI) \
  asm volatile("ds_write2_b32 %0, %1, %2 offset1:1" :: "v"(ADDR), "v"(LO), "v"(HI) : "memory")
#define DSWRITE128(ADDR, DATA) \
  asm volatile("ds_write_b128 %0, %1" :: "v"(ADDR), "v"(DATA) : "memory")
#define DSREAD128(DST, ADDR) \
  asm volatile("ds_read_b128 %0, %1" : "=v"(DST) : "v"(ADDR))
#define WAIT_VM(N)  asm volatile("s_waitcnt vmcnt(" #N ")" ::: "memory")
#define WAIT_LGKM() asm volatile("s_waitcnt lgkmcnt(0)" ::: "memory")
#define SB0()       __builtin_amdgcn_sched_barrier(0)

// one k-step's staging loads: A 4 x dwordx4 + B 16 x dword per thread (=20)
#define STAGE_ISSUE(RA, RB, T)                                                 \
  do {                                                                         \
    const float* pa_ = gAthr + (size_t)(T) * BK;                               \
    const float* pb_ = gBthr + (size_t)(T) * BK * ND;                          \
    GLOADX4(RA[0], pa_);                 GLOADX4(RA[1], pa_ + 64 * NL);        \
    GLOADX4(RA[2], pa_ + 128 * NL);      GLOADX4(RA[3], pa_ + 192 * NL);       \
    _Pragma("unroll") for (int i_ = 0; i_ < 16; ++i_)                          \
        GLOADX1(RB[i_], pb_ + (size_t)i_ * ND);                                \
  } while (0)

// convert staged regs to bf16 and write into LDS buffer at BUFOFF
#define STAGE_WRITE(RA, RB, BUFOFF)                                            \
  do {                                                                         \
    _Pragma("unroll") for (int i_ = 0; i_ < 4; ++i_) {                         \
      unsigned lo_ = bfbits(RA[i_][0]) | (bfbits(RA[i_][1]) << 16);            \
      unsigned hi_ = bfbits(RA[i_][2]) | (bfbits(RA[i_][3]) << 16);            \
      DSWRITE64(awAddr[i_] + (BUFOFF), lo_, hi_);                              \
    }                                                                          \
    _Pragma("unroll") for (int i_ = 0; i_ < 2; ++i_) {                         \
      u32x4 w_;                                                                \
      _Pragma("unroll") for (int j_ = 0; j_ < 4; ++j_)                         \
          w_[j_] = bfbits(RB[8 * i_ + 2 * j_]) |                               \
                   (bfbits(RB[8 * i_ + 2 * j_ + 1]) << 16);                    \
      DSWRITE128(bwAddr[i_] + (BUFOFF), w_);                                   \
    }                                                                          \
  } while (0)

// frag reads (8 A + 4 B, plain b128) + 32 MFMA from buffer at BUFOFF
#define COMPUTE(BUFOFF)                                                        \
  do {                                                                         \
    bf16x8 af_[8], bf_[4];                                                     \
    _Pragma("unroll") for (int m_ = 0; m_ < 8; ++m_)                           \
        DSREAD128(af_[m_], aRd[m_] + (BUFOFF));                                \
    _Pragma("unroll") for (int n_ = 0; n_ < 4; ++n_)                           \
        DSREAD128(bf_[n_], bRd[n_] + (BUFOFF));                                \
    WAIT_LGKM();                                                               \
    SB0();                                                                     \
    __builtin_amdgcn_s_setprio(1);                                             \
    _Pragma("unroll") for (int n_ = 0; n_ < 4; ++n_)                           \
        _Pragma("unroll") for (int m_ = 0; m_ < 8; ++m_)                       \
            acc[m_][n_] = __builtin_amdgcn_mfma_f32_16x16x32_bf16(             \
                af_[m_], bf_[n_], acc[m_][n_], 0, 0, 0);                       \
    __builtin_amdgcn_s_setprio(0);                                             \
    SB0();                                                                     \
  } while (0)

__global__ __launch_bounds__(512, 2) void mp_gemm(const float* __restrict__ doc,
                                                  const float* __restrict__ emap,
                                                  const float* __restrict__ lens,
                                                  float* __restrict__ out) {
  // 2 bufs x (A' [256r][32k] bf16 16KB + B' [256d][32k] bf16 16KB) = 64KB
  __shared__ char smem[2 * 32768];

  int bid = (int)blockIdx.x;
  // XCD swizzle: XCD x owns logical [16x,16x+15] = 2 whole batches.
  int logical = (bid & 7) * 16 + (bid >> 3);
  int b  = logical >> 3;      // 16 batches
  int dt = (logical >> 2) & 1;  // d-tile of 256
  int ks = logical & 3;       // k-split; siblings same XCD

  int tid  = (int)threadIdx.x;
  int w    = tid >> 6;
  int wr   = w >> 2;          // wave row 0..1 (128 rows each)
  int wc   = w & 3;           // wave col 0..3 (64 cols each)
  int lane = tid & 63;
  int l15  = lane & 15;
  int g    = lane >> 4;

  unsigned ldsb = lds_u32(smem);

  // ---- staging addresses ----
  // A: thread covers rows (tid>>3)+64i, 16B chunk (tid&7) of the 128B k-slice
  const float* gAthr = emap + (size_t)(b * NE + (tid >> 3)) * NL +
                       ks * KPW + (tid & 7) * 4;
  // B: thread owns d-column (tid>>1), k-half (tid&1): 16 k-rows of one dword
  const float* gBthr = doc +
      ((size_t)b * NL + ks * KPW + 16 * (tid & 1)) * ND + dt * 256 + (tid >> 1);

  // A' write: [row][32k] bf16 (64B rows); 16B-granule swizzle ^=(row>>1)&3.
  // thread writes kappa=4h..4h+3 (h=tid&7): granule h>>1, byte-in (h&1)*8.
  unsigned awAddr[4];
#pragma unroll
  for (int i = 0; i < 4; ++i) {
    int row = (tid >> 3) + 64 * i;
    int h = tid & 7;
    awAddr[i] = ldsb + row * 64 + (((h >> 1) ^ ((row >> 1) & 3)) << 4) + (h & 1) * 8;
  }
  // B' write: [d][32k] bf16 at 16384; chunk c (16B=8k) swizzled c^=(d>>2)&3
  unsigned bwAddr[2];
  {
    int d = tid >> 1;
#pragma unroll
    for (int i = 0; i < 2; ++i) {
      int c = 2 * (tid & 1) + i;
      bwAddr[i] = ldsb + 16384 + d * 64 + ((c ^ ((d >> 2) & 3)) << 4);
    }
  }

  // ---- fragment read addresses (both plain b128) ----
  unsigned aRd[8], bRd[4];
#pragma unroll
  for (int m = 0; m < 8; ++m) {
    int row = 128 * wr + 16 * m + l15;
    aRd[m] = ldsb + row * 64 + (((g ^ ((row >> 1) & 3)) & 3) << 4);
  }
#pragma unroll
  for (int n = 0; n < 4; ++n) {
    int d = 64 * wc + 16 * n + l15;
    bRd[n] = ldsb + 16384 + d * 64 + ((g ^ ((d >> 2) & 3)) << 4);
  }

  f32x4 acc[8][4] = {};
  f32x4 RA0[4], RA1[4];
  float RB0[16], RB1[16];

  // prologue: S0<-tile0, S1<-tile1; buf0 <- S0
  STAGE_ISSUE(RA0, RB0, 0);
  SB0();
  STAGE_ISSUE(RA1, RB1, 1);
  SB0();
  WAIT_VM(20);                 // tile0's 20 loads landed
  SB0();
  STAGE_WRITE(RA0, RB0, 0);

#pragma unroll 1
  for (int t = 0; t < NT; t += 2) {
    int p2 = t + 2 < NT ? t + 2 : NT - 1;  // clamped prefetch (tail-safe)
    int p3 = t + 3 < NT ? t + 3 : NT - 1;
    // even: compute buf0(t); issue S0<-t+2; wait S1(t+1); write buf1 <- S1
    WAIT_LGKM();
    __builtin_amdgcn_s_barrier();
    SB0();
    COMPUTE(0);
    STAGE_ISSUE(RA0, RB0, p2);
    SB0();
    WAIT_VM(20);
    SB0();
    STAGE_WRITE(RA1, RB1, 32768);
    // odd: compute buf1(t+1); issue S1<-t+3; wait S0(t+2); write buf0 <- S0
    WAIT_LGKM();
    __builtin_amdgcn_s_barrier();
    SB0();
    COMPUTE(32768);
    STAGE_ISSUE(RA1, RB1, p3);
    SB0();
    WAIT_VM(20);
    SB0();
    STAGE_WRITE(RA0, RB0, 0);
  }

  WAIT_VM(0);   // dangling clamped prefetches must land before regs reused
  SB0();

  // epilogue: divide by lens, atomic-accumulate the k-split partial.
  // C/D frag: row = 128wr + 16m + 4g + i, col = dt*256 + 64wc + 16n + l15.
  const float* lb = lens + b * NE + 128 * wr;
  float* ob = out + (size_t)(b * NE + 128 * wr) * ND + dt * 256 + 64 * wc;
#pragma unroll
  for (int m = 0; m < 8; ++m) {
#pragma unroll
    for (int i = 0; i < 4; ++i) {
      int row = 16 * m + 4 * g + i;
      float inv = 1.0f / lb[row];
#pragma unroll
      for (int n = 0; n < 4; ++n)
        unsafeAtomicAdd(&ob[(size_t)row * ND + 16 * n + l15], acc[m][n][i] * inv);
    }
  }
}

extern "C" void kernel_launch(void* const* d_in, const int* in_sizes, int n_in,
                              void* d_out, int out_size, void* d_ws, size_t ws_size,
                              hipStream_t stream) {
  const float* doc  = (const float*)d_in[0];  // (B, L, D)
  const float* emap = (const float*)d_in[1];  // (B, E, L)
  const float* lens = (const float*)d_in[2];  // (B, E)
  float* out = (float*)d_out;                 // (B, E, D)
  hipMemsetAsync(out, 0, (size_t)NB * NE * ND * sizeof(float), stream);
  hipLaunchKernelGGL(mp_gemm, dim3(128), dim3(512), 0, stream, doc, emap, lens, out);
}

// Round 10
// 63.908 us; speedup vs baseline: 1.4110x; 1.4110x over previous
//
#include <hip/hip_runtime.h>
#include <hip/hip_bf16.h>

// MeanPooling: out[b,e,d] = (sum_l map[b,e,l]*doc[b,l,d]) / lens[b,e]
// B=16, E=256, L=4096 (=K), D=512. fp32 in/out, bf16 MFMA inside.
//
// R10 = R9 with __launch_bounds__(256,2) restored. R9's NaN: bounds (256,3)
// capped VGPR at ~168 < ~170+ live -> spills; RS0/RS1 are destinations of
// in-flight asm global_loads, and a spill between issue and s_waitcnt saves
// stale register bits (no VMEM interlock on CDNA) -> garbage bf16 -> NaN.
// At bound 2 (256 VGPR) nothing spills (R7:100, R8:128 VGPR).
//
// Structure (R9): per-CU VMEM *instruction rate* experiment. R7 geometry
// (512 blocks, 128x128 tile, split-K x4); role-split staging: waves 0-1
// stage B, waves 2-3 stage A; 8 x dwordx4 (16B/lane) per wave per k-step
// (vs R7's 20 mixed-width); cvt-at-staging; frags read straight as bf16.
//  - A' [128row][32k] bf16, granule swizzle ^=(row&3); writes ds_write_b64.
//  - B' [128d][32k] bf16 (write-side transpose), granule swizzle ^=(d>>2)&3;
//    writes ds_write_b128. Frag reads 4+4 ds_read_b128, conflict-free.
//  - Depth-2 LDS pingpong, counted vmcnt(8), raw s_barrier, clamped tail,
//    memsetAsync + unsafeAtomicAdd split-K epilogue (R7-verified).

#define NB 16
#define NE 256
#define NL 4096
#define ND 512
#define KSPLIT 4
#define KPW (NL / KSPLIT)   // 1024 per block
#define BK 32
#define NT (KPW / BK)       // 32 k-steps

using f32x4  = __attribute__((ext_vector_type(4))) float;
using u32x2  = __attribute__((ext_vector_type(2))) unsigned;
using u32x4  = __attribute__((ext_vector_type(4))) unsigned;
using bf16x8 = __attribute__((ext_vector_type(8))) short;

static __device__ __forceinline__ unsigned bfbits(float x) {
  return (unsigned)__builtin_bit_cast(unsigned short, (__bf16)x);  // RNE
}
static __device__ __forceinline__ unsigned lds_u32(const void* p) {
  return (unsigned)(size_t)(const __attribute__((address_space(3))) void*)p;
}

#define GLOADX4(DST, PTR) \
  asm volatile("global_load_dwordx4 %0, %1, off" : "=v"(DST) : "v"(PTR))
#define DSW64(ADDR, D, OFF) \
  asm volatile("ds_write_b64 %0, %1 offset:" OFF :: "v"(ADDR), "v"(D) : "memory")
#define DSW128(ADDR, D, OFF) \
  asm volatile("ds_write_b128 %0, %1 offset:" OFF :: "v"(ADDR), "v"(D) : "memory")
#define DSR128(DST, ADDR, OFF) \
  asm volatile("ds_read_b128 %0, %1 offset:" OFF : "=v"(DST) : "v"(ADDR))
#define WAIT_VM(N)  asm volatile("s_waitcnt vmcnt(" #N ")" ::: "memory")
#define WAIT_LGKM() asm volatile("s_waitcnt lgkmcnt(0)" ::: "memory")
#define SB0()       __builtin_amdgcn_sched_barrier(0)

// one k-step's staging: 8 x dwordx4 per thread (role decides addresses)
#define STAGE_ISSUE(RS, T)                                                     \
  do {                                                                         \
    const float* p_ = gthr + (size_t)(T) * tstep;                              \
    GLOADX4(RS[0], p_ + st0[0]); GLOADX4(RS[1], p_ + st0[1]);                  \
    GLOADX4(RS[2], p_ + st0[2]); GLOADX4(RS[3], p_ + st0[3]);                  \
    GLOADX4(RS[4], p_ + st0[4]); GLOADX4(RS[5], p_ + st0[5]);                  \
    GLOADX4(RS[6], p_ + st0[6]); GLOADX4(RS[7], p_ + st0[7]);                  \
  } while (0)

// convert to bf16 and write into LDS buffer (OFFS = "0" or "16384")
#define STAGE_WRITE(RS, OFFS)                                                  \
  do {                                                                         \
    if (isB) {                                                                 \
      _Pragma("unroll") for (int j_ = 0; j_ < 4; ++j_) {                       \
        u32x4 wv_;                                                             \
        _Pragma("unroll") for (int k_ = 0; k_ < 4; ++k_)                       \
            wv_[k_] = bfbits(RS[2 * k_][j_]) | (bfbits(RS[2 * k_ + 1][j_]) << 16); \
        DSW128(wAddr[j_], wv_, OFFS);                                          \
      }                                                                        \
    } else {                                                                   \
      _Pragma("unroll") for (int i_ = 0; i_ < 8; ++i_) {                       \
        u32x2 wv_;                                                             \
        wv_[0] = bfbits(RS[i_][0]) | (bfbits(RS[i_][1]) << 16);                \
        wv_[1] = bfbits(RS[i_][2]) | (bfbits(RS[i_][3]) << 16);                \
        DSW64(wAddr[i_], wv_, OFFS);                                           \
      }                                                                        \
    }                                                                          \
  } while (0)

// frag reads (4 A + 4 B b128) + 16 MFMA from buffer at OFFS
#define COMPUTE(OFFS)                                                          \
  do {                                                                         \
    bf16x8 af_[4], bf_[4];                                                     \
    DSR128(af_[0], aRd[0], OFFS); DSR128(af_[1], aRd[1], OFFS);                \
    DSR128(af_[2], aRd[2], OFFS); DSR128(af_[3], aRd[3], OFFS);                \
    DSR128(bf_[0], bRd[0], OFFS); DSR128(bf_[1], bRd[1], OFFS);                \
    DSR128(bf_[2], bRd[2], OFFS); DSR128(bf_[3], bRd[3], OFFS);                \
    WAIT_LGKM();                                                               \
    SB0();                                                                     \
    __builtin_amdgcn_s_setprio(1);                                             \
    _Pragma("unroll") for (int m_ = 0; m_ < 4; ++m_)                           \
        _Pragma("unroll") for (int n_ = 0; n_ < 4; ++n_)                       \
            acc[m_][n_] = __builtin_amdgcn_mfma_f32_16x16x32_bf16(             \
                af_[m_], bf_[n_], acc[m_][n_], 0, 0, 0);                       \
    __builtin_amdgcn_s_setprio(0);                                             \
    SB0();                                                                     \
  } while (0)

__global__ __launch_bounds__(256, 2) void mp_gemm(const float* __restrict__ doc,
                                                  const float* __restrict__ emap,
                                                  const float* __restrict__ lens,
                                                  float* __restrict__ out) {
  // 2 bufs x (A' [128r][32k] bf16 8KB + B' [128d][32k] bf16 8KB) = 32KB
  __shared__ char smem[2 * 16384];

  int bid = (int)blockIdx.x;
  // XCD swizzle: XCD x owns logical [64x,64x+63] = 2 whole batches.
  int logical = (bid & 7) * 64 + (bid >> 3);
  int b    = logical >> 5;
  int rest = logical & 31;
  int et = rest >> 4;         // e-tile of 128 (2)
  int dt = (rest >> 2) & 3;   // d-tile of 128 (4)
  int ks = rest & 3;          // k-split (4); siblings adjacent -> same XCD

  int tid  = (int)threadIdx.x;
  int w    = tid >> 6;
  int wr   = w >> 1;          // wave row 0..1 (64 rows)
  int wc   = w & 1;           // wave col 0..1 (64 cols)
  int lane = tid & 63;
  int l15  = lane & 15;
  int g    = lane >> 4;

  unsigned ldsb = lds_u32(smem);
  bool isB = (tid < 128);     // waves 0-1 stage B, waves 2-3 stage A

  // ---- staging addresses (per role) ----
  const float* gthr;          // per-thread base at tile 0
  size_t tstep = (size_t)BK;  // elements per k-step in the load dimension
  int st0[8];                 // per-instr element offsets
  unsigned wAddr[8];          // LDS write addresses (buf0)

  if (isB) {
    // thread owns d = 4q..4q+3, k = 8o..8o+7 (q=tid&31, o=tid>>5)
    int q = tid & 31, o = tid >> 5;
    gthr = doc + ((size_t)b * NL + ks * KPW + 8 * o) * ND + dt * 128 + 4 * q;
    tstep = (size_t)BK * ND;
#pragma unroll
    for (int i = 0; i < 8; ++i) st0[i] = i * ND;
    // B' write: col d=4q+j holds k-octet o (16B granule), swz o^(q&3)
#pragma unroll
    for (int j = 0; j < 4; ++j)
      wAddr[j] = ldsb + 8192 + (4 * q + j) * 64 + (((o ^ q) & 3) << 4);
  } else {
    // thread owns rows 32r+(v>>2), chunks 4h+(v&3) (r 0..3, h 0..1)
    int v = tid - 128;
    int rowb = v >> 2, ch = v & 3;
    gthr = emap + (size_t)(b * NE + et * 128 + rowb) * NL + ks * KPW + 4 * ch;
    tstep = (size_t)BK;
#pragma unroll
    for (int r = 0; r < 4; ++r)
#pragma unroll
      for (int h = 0; h < 2; ++h) st0[2 * r + h] = r * 32 * NL + h * 16;
    // A' write: row 32r+rowb, granule c16=2h+(ch>>1), swz c16^(row&3), 8B parity ch&1
#pragma unroll
    for (int r = 0; r < 4; ++r)
#pragma unroll
      for (int h = 0; h < 2; ++h) {
        int row = 32 * r + rowb;
        int c16 = 2 * h + (ch >> 1);
        wAddr[2 * r + h] = ldsb + row * 64 + (((c16 ^ row) & 3) << 4) + (ch & 1) * 8;
      }
  }

  // ---- fragment read addresses (all waves; conflict-free swizzles) ----
  unsigned aRd[4], bRd[4];
#pragma unroll
  for (int m = 0; m < 4; ++m) {
    int row = 64 * wr + 16 * m + l15;
    aRd[m] = ldsb + row * 64 + (((g ^ row) & 3) << 4);
  }
#pragma unroll
  for (int n = 0; n < 4; ++n) {
    int d = 64 * wc + 16 * n + l15;
    bRd[n] = ldsb + 8192 + d * 64 + (((g ^ (d >> 2)) & 3) << 4);
  }

  f32x4 acc[4][4] = {};
  f32x4 RS0[8], RS1[8];

  // prologue: S0<-tile0, S1<-tile1; buf0 <- S0
  STAGE_ISSUE(RS0, 0);
  SB0();
  STAGE_ISSUE(RS1, 1);
  SB0();
  WAIT_VM(8);                  // tile0's 8 loads landed
  SB0();
  STAGE_WRITE(RS0, "0");

#pragma unroll 1
  for (int t = 0; t < NT; t += 2) {
    int p2 = t + 2 < NT ? t + 2 : NT - 1;  // clamped prefetch (tail-safe)
    int p3 = t + 3 < NT ? t + 3 : NT - 1;
    // even: compute buf0(t); issue S0<-t+2; wait t+1; write buf1 <- S1
    WAIT_LGKM();
    __builtin_amdgcn_s_barrier();
    SB0();
    STAGE_ISSUE(RS0, p2);
    SB0();
    COMPUTE("0");
    WAIT_VM(8);
    SB0();
    STAGE_WRITE(RS1, "16384");
    // odd: compute buf1(t+1); issue S1<-t+3; wait t+2; write buf0 <- S0
    WAIT_LGKM();
    __builtin_amdgcn_s_barrier();
    SB0();
    STAGE_ISSUE(RS1, p3);
    SB0();
    COMPUTE("16384");
    WAIT_VM(8);
    SB0();
    STAGE_WRITE(RS0, "0");
  }

  WAIT_VM(0);   // dangling clamped prefetches must land before regs reused
  SB0();

  // epilogue: divide by lens, atomic-accumulate the k-split partial.
  // C/D frag: row = 16m + 4g + i, col = 16n + l15 (within 64x64 quadrant).
  const float* lb = lens + b * NE + et * 128 + 64 * wr;
  float* ob = out + (size_t)(b * NE + et * 128 + 64 * wr) * ND + dt * 128 + 64 * wc;
#pragma unroll
  for (int m = 0; m < 4; ++m) {
#pragma unroll
    for (int i = 0; i < 4; ++i) {
      int row = 16 * m + 4 * g + i;
      float inv = 1.0f / lb[row];
#pragma unroll
      for (int n = 0; n < 4; ++n)
        unsafeAtomicAdd(&ob[(size_t)row * ND + 16 * n + l15], acc[m][n][i] * inv);
    }
  }
}

extern "C" void kernel_launch(void* const* d_in, const int* in_sizes, int n_in,
                              void* d_out, int out_size, void* d_ws, size_t ws_size,
                              hipStream_t stream) {
  const float* doc  = (const float*)d_in[0];  // (B, L, D)
  const float* emap = (const float*)d_in[1];  // (B, E, L)
  const float* lens = (const float*)d_in[2];  // (B, E)
  float* out = (float*)d_out;                 // (B, E, D)
  hipMemsetAsync(out, 0, (size_t)NB * NE * ND * sizeof(float), stream);
  hipLaunchKernelGGL(mp_gemm, dim3(512), dim3(256), 0, stream, doc, emap, lens, out);
}